// Round 1
// baseline (78.330 us; speedup 1.0000x reference)
//
#include <hip/hip_runtime.h>

// scores[b,n] = 0.125 * X[b,n,:] . t[b,:]
//   t[b,d]    = sum_c Wq[c,d] * v[b,c]
//   v[b,c]    = Wk[c,:] . Xsum[b,:]
//   Xsum[b,:] = sum_n X[b,n,:]
// Wq = W_qkv rows [0,768), Wk = W_qkv rows [768,1536). scale = 64^-0.5 = 0.125.

#define DIM 768
#define BATCH 2
#define SEQ 2048

// ws layout (floats): xsum[2*768] @ 0, v[2*768] @ 1536, t[2*768] @ 3072

// Kernel A: column sums of X per batch, split over n, atomicAdd into xsum.
__global__ void colsum_kernel(const float* __restrict__ X, float* __restrict__ xsum) {
    const int NSPLIT = 32;                 // grid = BATCH * 3 * NSPLIT = 192 blocks
    int bx = blockIdx.x;
    int b = bx / (3 * NSPLIT);
    int rem = bx % (3 * NSPLIT);
    int dchunk = rem % 3;
    int nchunk = rem / 3;
    int d = dchunk * 256 + threadIdx.x;    // 3 chunks of 256 cover 768
    const float* base = X + (size_t)b * SEQ * DIM + (size_t)nchunk * (SEQ / NSPLIT) * DIM + d;
    float acc = 0.f;
    #pragma unroll 8
    for (int n = 0; n < SEQ / NSPLIT; ++n)
        acc += base[(size_t)n * DIM];
    atomicAdd(&xsum[b * DIM + d], acc);
}

// Kernel B1: v[b,c] = Wk[c,:] . xsum[b,:]. One wave per output.
__global__ void kv_matvec_kernel(const float* __restrict__ W, const float* __restrict__ xsum,
                                 float* __restrict__ v) {
    int w = blockIdx.x * 4 + (threadIdx.x >> 6);   // wave id = output id
    int lane = threadIdx.x & 63;
    int b = w / DIM;
    int c = w % DIM;
    const float4* wrow = (const float4*)(W + (size_t)(DIM + c) * DIM);
    const float4* xs   = (const float4*)(xsum + b * DIM);
    float acc = 0.f;
    #pragma unroll
    for (int j = 0; j < 3; ++j) {                  // 192 float4 / 64 lanes
        float4 a = wrow[lane + 64 * j];
        float4 s = xs[lane + 64 * j];
        acc += a.x * s.x + a.y * s.y + a.z * s.z + a.w * s.w;
    }
    #pragma unroll
    for (int off = 32; off > 0; off >>= 1)
        acc += __shfl_down(acc, off, 64);
    if (lane == 0) v[b * DIM + c] = acc;
}

// Kernel B2: t[b,d] = sum_c Wq[c,d] * v[b,c], split over c, atomicAdd into t.
__global__ void wq_t_matvec_kernel(const float* __restrict__ W, const float* __restrict__ v,
                                   float* __restrict__ t) {
    const int CSPLIT = 8;                  // grid = BATCH * 3 * CSPLIT = 48 blocks
    int bx = blockIdx.x;
    int b = bx / (3 * CSPLIT);
    int rem = bx % (3 * CSPLIT);
    int dchunk = rem % 3;
    int cchunk = rem / 3;
    int d = dchunk * 256 + threadIdx.x;
    const float* vb = v + b * DIM;
    float acc = 0.f;
    int c0 = cchunk * (DIM / CSPLIT);
    #pragma unroll 8
    for (int c = c0; c < c0 + DIM / CSPLIT; ++c)
        acc += W[(size_t)c * DIM + d] * vb[c];   // coalesced across threads per c
    atomicAdd(&t[b * DIM + d], acc);
}

// Kernel C: out[b,n] = 0.125 * X[b,n,:] . t[b,:]. One wave per row.
__global__ void scores_kernel(const float* __restrict__ X, const float* __restrict__ t,
                              float* __restrict__ out) {
    int r = blockIdx.x * 4 + (threadIdx.x >> 6);   // 0..4095
    int lane = threadIdx.x & 63;
    int b = r >> 11;                               // r / 2048
    const float4* xr = (const float4*)(X + (size_t)r * DIM);
    const float4* tb = (const float4*)(t + b * DIM);
    float acc = 0.f;
    #pragma unroll
    for (int j = 0; j < 3; ++j) {
        float4 a = xr[lane + 64 * j];
        float4 s = tb[lane + 64 * j];
        acc += a.x * s.x + a.y * s.y + a.z * s.z + a.w * s.w;
    }
    #pragma unroll
    for (int off = 32; off > 0; off >>= 1)
        acc += __shfl_down(acc, off, 64);
    if (lane == 0) out[r] = 0.125f * acc;
}

extern "C" void kernel_launch(void* const* d_in, const int* in_sizes, int n_in,
                              void* d_out, int out_size, void* d_ws, size_t ws_size,
                              hipStream_t stream) {
    const float* X = (const float*)d_in[0];   // [2, 2048, 768]
    const float* W = (const float*)d_in[1];   // [1536, 768]
    float* out = (float*)d_out;               // [2, 2048]
    float* ws = (float*)d_ws;
    float* xsum = ws;                         // [2, 768]
    float* v    = ws + 2 * DIM;               // [2, 768]
    float* t    = ws + 4 * DIM;               // [2, 768]

    hipMemsetAsync(d_ws, 0, 6 * DIM * sizeof(float), stream);  // zero xsum/v/t (ws is poisoned)

    colsum_kernel<<<BATCH * 3 * 32, 256, 0, stream>>>(X, xsum);
    kv_matvec_kernel<<<BATCH * DIM / 4, 256, 0, stream>>>(W, xsum, v);
    wq_t_matvec_kernel<<<BATCH * 3 * 8, 256, 0, stream>>>(W, v, t);
    scores_kernel<<<BATCH * SEQ / 4, 256, 0, stream>>>(X, t, out);
}